// Round 1
// baseline (458.760 us; speedup 1.0000x reference)
//
#include <hip/hip_runtime.h>
#include <float.h>
#include <math.h>

// Problem constants (fixed by reference setup_inputs)
constexpr int NQ = 2048;    // queries
constexpr int ND = 65536;   // data points
constexpr int D  = 16;      // dims
constexpr int QB = 16;      // queries per block
constexpr int S  = 8;       // data chunks (grid.y)
constexpr int BT = 256;     // threads per block
constexpr int P  = 2;       // points per thread per iteration
constexpr int PTS = ND / S;              // 8192 points per block
constexpr int ITERS = PTS / (BT * P);    // 16

// Kernel 1: partial min over (d^2 - 2*x.d) for a (16-query, 8192-point) tile.
// x^2 is added in kernel 2 (constant per query -> same argmin).
__global__ __launch_bounds__(BT) void knn_partial(const float* __restrict__ x,
                                                  const float* __restrict__ data,
                                                  float* __restrict__ ws) {
    const int qbase = blockIdx.x * QB;
    const int pbase = blockIdx.y * PTS;
    const int t     = threadIdx.x;

    float acc[QB];
#pragma unroll
    for (int q = 0; q < QB; ++q) acc[q] = FLT_MAX;

    for (int it = 0; it < ITERS; ++it) {
        float pt[P][D];
        float nrm[P];
#pragma unroll
        for (int j = 0; j < P; ++j) {
            const int p = pbase + (it * P + j) * BT + t;
            const float4* row = (const float4*)(data + (size_t)p * D);
            float4 a = row[0], b = row[1], c = row[2], e = row[3];
            pt[j][0]  = a.x; pt[j][1]  = a.y; pt[j][2]  = a.z; pt[j][3]  = a.w;
            pt[j][4]  = b.x; pt[j][5]  = b.y; pt[j][6]  = b.z; pt[j][7]  = b.w;
            pt[j][8]  = c.x; pt[j][9]  = c.y; pt[j][10] = c.z; pt[j][11] = c.w;
            pt[j][12] = e.x; pt[j][13] = e.y; pt[j][14] = e.z; pt[j][15] = e.w;
            float n = 0.f;
#pragma unroll
            for (int k = 0; k < D; ++k) n = fmaf(pt[j][k], pt[j][k], n);
            nrm[j] = n;
        }
#pragma unroll
        for (int q = 0; q < QB; ++q) {
            // Wave-uniform query row -> expect s_load_dwordx4 (scalar pipe)
            const float4* xr = (const float4*)(x + (size_t)(qbase + q) * D);
            float4 xa = xr[0], xb = xr[1], xc = xr[2], xe = xr[3];
            const float xq[D] = {xa.x, xa.y, xa.z, xa.w, xb.x, xb.y, xb.z, xb.w,
                                 xc.x, xc.y, xc.z, xc.w, xe.x, xe.y, xe.z, xe.w};
#pragma unroll
            for (int j = 0; j < P; ++j) {
                float dot = 0.f;
#pragma unroll
                for (int k = 0; k < D; ++k) dot = fmaf(xq[k], pt[j][k], dot);
                acc[q] = fminf(acc[q], fmaf(-2.f, dot, nrm[j]));
            }
        }
    }

    // Block reduction: wave-level butterfly min, then cross-wave via LDS.
    __shared__ float red[BT / 64][QB];
    const int lane = t & 63;
    const int wave = t >> 6;
#pragma unroll
    for (int q = 0; q < QB; ++q) {
        float v = acc[q];
#pragma unroll
        for (int m = 32; m >= 1; m >>= 1) v = fminf(v, __shfl_xor(v, m, 64));
        if (lane == 0) red[wave][q] = v;
    }
    __syncthreads();
    if (t < QB) {
        float v = red[0][t];
#pragma unroll
        for (int w = 1; w < BT / 64; ++w) v = fminf(v, red[w][t]);
        ws[(size_t)blockIdx.y * NQ + qbase + t] = v;
    }
}

// Kernel 2: final min across chunks + ||x||^2 + bump function.
__global__ __launch_bounds__(256) void knn_final(const float* __restrict__ x,
                                                 const float* __restrict__ ws,
                                                 float* __restrict__ out) {
    const int q = blockIdx.x * 256 + threadIdx.x;
    if (q >= NQ) return;

    const float4* xr = (const float4*)(x + (size_t)q * D);
    float4 a = xr[0], b = xr[1], c = xr[2], e = xr[3];
    float x2 = 0.f;
    x2 = fmaf(a.x, a.x, x2); x2 = fmaf(a.y, a.y, x2);
    x2 = fmaf(a.z, a.z, x2); x2 = fmaf(a.w, a.w, x2);
    x2 = fmaf(b.x, b.x, x2); x2 = fmaf(b.y, b.y, x2);
    x2 = fmaf(b.z, b.z, x2); x2 = fmaf(b.w, b.w, x2);
    x2 = fmaf(c.x, c.x, x2); x2 = fmaf(c.y, c.y, x2);
    x2 = fmaf(c.z, c.z, x2); x2 = fmaf(c.w, c.w, x2);
    x2 = fmaf(e.x, e.x, x2); x2 = fmaf(e.y, e.y, x2);
    x2 = fmaf(e.z, e.z, x2); x2 = fmaf(e.w, e.w, x2);

    float m = FLT_MAX;
#pragma unroll
    for (int cI = 0; cI < S; ++cI) m = fminf(m, ws[(size_t)cI * NQ + q]);

    // nn2 = max(min dist2, 0); dist = sqrt(max(nn2, 1e-12))
    float nn2  = fmaxf(m + x2, 0.f);
    float dist = sqrtf(fmaxf(nn2, 1e-12f));

    float bump = 0.f;
    if (dist < 2.0f) {  // RADIUS = 2
        float denom = dist * dist - 4.0f;           // d^2 - r^2
        bump = expf(1.0f / denom + 0.25f);          // DECAY/denom + DECAY/r^2
    }
    out[q] = bump;
}

extern "C" void kernel_launch(void* const* d_in, const int* in_sizes, int n_in,
                              void* d_out, int out_size, void* d_ws, size_t ws_size,
                              hipStream_t stream) {
    const float* x    = (const float*)d_in[0];   // [2048,16] fp32
    const float* data = (const float*)d_in[1];   // [65536,16] fp32
    float* out = (float*)d_out;                  // [2048] fp32
    float* ws  = (float*)d_ws;                   // needs 8*2048*4 = 64 KB

    dim3 g1(NQ / QB, S);                         // 128 x 8 = 1024 blocks
    knn_partial<<<g1, BT, 0, stream>>>(x, data, ws);
    knn_final<<<NQ / 256, 256, 0, stream>>>(x, ws, out);
}

// Round 2
// 183.341 us; speedup vs baseline: 2.5022x; 2.5022x over previous
//
#include <hip/hip_runtime.h>
#include <float.h>
#include <math.h>

// Problem constants (fixed by reference setup_inputs)
constexpr int NQ = 2048;    // queries
constexpr int ND = 65536;   // data points
constexpr int D  = 16;      // dims

// ---------------------------------------------------------------------------
// Kernel 0: nhn[p] = -0.5 * ||data_p||^2   (seed for the dot-product chain)
// ---------------------------------------------------------------------------
__global__ __launch_bounds__(256) void neg_half_norms(const float* __restrict__ data,
                                                      float* __restrict__ nhn) {
    const int p = blockIdx.x * 256 + threadIdx.x;
    const float4* r = (const float4*)(data + (size_t)p * D);
    float4 a = r[0], b = r[1], c = r[2], e = r[3];
    float n = a.x * a.x;
    n = fmaf(a.y, a.y, n); n = fmaf(a.z, a.z, n); n = fmaf(a.w, a.w, n);
    n = fmaf(b.x, b.x, n); n = fmaf(b.y, b.y, n); n = fmaf(b.z, b.z, n); n = fmaf(b.w, b.w, n);
    n = fmaf(c.x, c.x, n); n = fmaf(c.y, c.y, n); n = fmaf(c.z, c.z, n); n = fmaf(c.w, c.w, n);
    n = fmaf(e.x, e.x, n); n = fmaf(e.y, e.y, n); n = fmaf(e.z, e.z, n); n = fmaf(e.w, e.w, n);
    nhn[p] = -0.5f * n;
}

// ---------------------------------------------------------------------------
// Kernel 1: one thread = one query. Points + norms are wave-uniform -> scalar
// loads (s_load_dwordx16) on the scalar pipe, co-issuing with VALU.
// Computes best = max_p (x.p - 0.5*||p||^2) over this block's point chunk.
// (argmin of dist2 == argmax of this; dist2 = ||x||^2 - 2*best.)
// Per point: 16 v_fma (two 8-chains, one seeded with nhn) + add + max = 18 VALU.
// ---------------------------------------------------------------------------
__global__ __launch_bounds__(256) void knn_partial(const float* __restrict__ x,
                                                   const float* __restrict__ data,
                                                   const float* __restrict__ nhn,
                                                   float* __restrict__ part,
                                                   int cp /* points per chunk */) {
    const int q     = blockIdx.x * 256 + threadIdx.x;   // this thread's query
    const int pbase = blockIdx.y * cp;

    const float4* xr = (const float4*)(x + (size_t)q * D);
    const float4 xa = xr[0], xb = xr[1], xc = xr[2], xd = xr[3];

    const float* dp = data + (size_t)pbase * D;  // uniform across wave
    const float* np = nhn + pbase;               // uniform across wave

    float best = -FLT_MAX;

    for (int i = 0; i < cp; i += 4) {
#pragma unroll
        for (int j = 0; j < 4; ++j) {
            const float* r  = dp + (size_t)(i + j) * D;   // uniform -> s_load
            const float  hn = np[i + j];                  // uniform -> s_load
            // chain A: dims 0..7
            float ca = xa.x * r[0];
            ca = fmaf(xa.y, r[1], ca);
            ca = fmaf(xa.z, r[2], ca);
            ca = fmaf(xa.w, r[3], ca);
            ca = fmaf(xb.x, r[4], ca);
            ca = fmaf(xb.y, r[5], ca);
            ca = fmaf(xb.z, r[6], ca);
            ca = fmaf(xb.w, r[7], ca);
            // chain B: dims 8..15, seeded with -0.5*||p||^2
            float cb = fmaf(xc.x, r[8], hn);
            cb = fmaf(xc.y, r[9],  cb);
            cb = fmaf(xc.z, r[10], cb);
            cb = fmaf(xc.w, r[11], cb);
            cb = fmaf(xd.x, r[12], cb);
            cb = fmaf(xd.y, r[13], cb);
            cb = fmaf(xd.z, r[14], cb);
            cb = fmaf(xd.w, r[15], cb);
            best = fmaxf(best, ca + cb);
        }
    }
    // one partial per (chunk, query); coalesced across threads
    part[(size_t)blockIdx.y * NQ + q] = best;
}

// ---------------------------------------------------------------------------
// Kernel 2: reduce chunks, add ||x||^2, bump function.
// ---------------------------------------------------------------------------
__global__ __launch_bounds__(256) void knn_final(const float* __restrict__ x,
                                                 const float* __restrict__ part,
                                                 float* __restrict__ out, int S) {
    const int q = blockIdx.x * 256 + threadIdx.x;

    const float4* xr = (const float4*)(x + (size_t)q * D);
    float4 a = xr[0], b = xr[1], c = xr[2], e = xr[3];
    float x2 = a.x * a.x;
    x2 = fmaf(a.y, a.y, x2); x2 = fmaf(a.z, a.z, x2); x2 = fmaf(a.w, a.w, x2);
    x2 = fmaf(b.x, b.x, x2); x2 = fmaf(b.y, b.y, x2); x2 = fmaf(b.z, b.z, x2); x2 = fmaf(b.w, b.w, x2);
    x2 = fmaf(c.x, c.x, x2); x2 = fmaf(c.y, c.y, x2); x2 = fmaf(c.z, c.z, x2); x2 = fmaf(c.w, c.w, x2);
    x2 = fmaf(e.x, e.x, x2); x2 = fmaf(e.y, e.y, x2); x2 = fmaf(e.z, e.z, x2); x2 = fmaf(e.w, e.w, x2);

    float m = -FLT_MAX;
    for (int cI = 0; cI < S; ++cI) m = fmaxf(m, part[(size_t)cI * NQ + q]);

    // dist2 = ||x||^2 - 2*best ; clamp like the reference
    float nn2  = fmaxf(fmaf(-2.f, m, x2), 0.f);
    float dist = sqrtf(fmaxf(nn2, 1e-12f));

    float bump = 0.f;
    if (dist < 2.0f) {                      // RADIUS = 2
        float denom = dist * dist - 4.0f;   // d^2 - r^2
        bump = expf(1.0f / denom + 0.25f);  // DECAY/denom + DECAY/r^2
    }
    out[q] = bump;
}

extern "C" void kernel_launch(void* const* d_in, const int* in_sizes, int n_in,
                              void* d_out, int out_size, void* d_ws, size_t ws_size,
                              hipStream_t stream) {
    const float* x    = (const float*)d_in[0];   // [2048,16] fp32
    const float* data = (const float*)d_in[1];   // [65536,16] fp32
    float* out = (float*)d_out;                  // [2048] fp32

    // Workspace layout: [0, ND) = neg-half norms; [ND, ND + S*NQ) = partials.
    // Pick the largest chunk count S that fits the provided workspace.
    int S = 256;
    while (S > 1 && (size_t)(ND + S * NQ) * sizeof(float) > ws_size) S >>= 1;
    const int cp = ND / S;

    float* nhn  = (float*)d_ws;
    float* part = (float*)d_ws + ND;

    neg_half_norms<<<ND / 256, 256, 0, stream>>>(data, nhn);
    knn_partial<<<dim3(NQ / 256, S), 256, 0, stream>>>(x, data, nhn, part, cp);
    knn_final<<<NQ / 256, 256, 0, stream>>>(x, part, out, S);
}

// Round 3
// 90.347 us; speedup vs baseline: 5.0778x; 2.0293x over previous
//
#include <hip/hip_runtime.h>
#include <float.h>
#include <math.h>

// Problem constants (fixed by reference setup_inputs)
constexpr int NQ = 2048;    // queries
constexpr int ND = 65536;   // data points
constexpr int D  = 16;      // dims

// ---- MFMA-path tiling ----
constexpr int SCH = 64;           // point chunks (grid.y)
constexpr int CP  = ND / SCH;     // 1024 points per chunk
constexpr int TPW = CP / 32;      // 32 point-tiles (32 pts each) per wave

typedef short bf16x8 __attribute__((ext_vector_type(8)));
typedef float f32x16 __attribute__((ext_vector_type(16)));

__device__ __forceinline__ unsigned short f2bf(float f) {  // RNE fp32->bf16
    unsigned u = __float_as_uint(f);
    u += 0x7FFFu + ((u >> 16) & 1u);
    return (unsigned short)(u >> 16);
}
__device__ __forceinline__ float bf2f(unsigned short h) {
    return __uint_as_float(((unsigned)h) << 16);
}

// ---------------------------------------------------------------------------
// Pack kernel: data -> Ppk[ND][32] = [ph(16)|pl(16)] bf16, nhf[ND] = -0.5*||p||^2
//              x    -> Apk[NQ][32] = [xh(16)|xl(16)] bf16
// ---------------------------------------------------------------------------
__global__ __launch_bounds__(256) void pack_inputs(const float* __restrict__ x,
                                                   const float* __restrict__ data,
                                                   unsigned short* __restrict__ Ppk,
                                                   unsigned short* __restrict__ Apk,
                                                   float* __restrict__ nhf) {
    const int idx = blockIdx.x * 256 + threadIdx.x;
    const float* src;
    unsigned short* dst;
    if (idx < ND) {
        src = data + (size_t)idx * D;
        dst = Ppk + (size_t)idx * 32;
    } else {
        const int q = idx - ND;
        if (q >= NQ) return;
        src = x + (size_t)q * D;
        dst = Apk + (size_t)q * 32;
    }
    const float4* r4 = (const float4*)src;
    float4 a = r4[0], b = r4[1], c = r4[2], e = r4[3];
    float v[16] = {a.x, a.y, a.z, a.w, b.x, b.y, b.z, b.w,
                   c.x, c.y, c.z, c.w, e.x, e.y, e.z, e.w};
    unsigned short row[32];
    float n = 0.f;
#pragma unroll
    for (int k = 0; k < 16; ++k) {
        n = fmaf(v[k], v[k], n);
        unsigned short h = f2bf(v[k]);
        row[k]      = h;
        row[16 + k] = f2bf(v[k] - bf2f(h));   // lo residual
    }
    uint4* w4 = (uint4*)dst;
    const uint4* r = (const uint4*)row;
    w4[0] = r[0]; w4[1] = r[1]; w4[2] = r[2]; w4[3] = r[3];
    if (idx < ND) nhf[idx] = -0.5f * n;
}

// ---------------------------------------------------------------------------
// Main kernel: per (32-query row-tile, point chunk) wave computes
//   best[q] = max_p ( x_q . p - 0.5*||p||^2 )
// via 3x mfma_f32_32x32x16_bf16 per 32-point tile, C seeded with -0.5*||p||^2.
// A-frag: m = lane&31, k = (lane>>5)*8 + j (contiguous). B-frag symmetric.
// C/D: col = lane&31, row = (reg&3) + 8*(reg>>2) + 4*(lane>>5)  [m74/m101].
// ---------------------------------------------------------------------------
__global__ __launch_bounds__(256) void knn_mfma(const unsigned short* __restrict__ Apk,
                                                const unsigned short* __restrict__ Ppk,
                                                const float* __restrict__ nhf,
                                                float* __restrict__ part) {
    const int tid  = threadIdx.x;
    const int w    = tid >> 6;
    const int l    = tid & 63;
    const int half = l >> 5;
    const int n31  = l & 31;
    const int qbase = blockIdx.x * 128 + w * 32;   // 4 waves x 32 queries
    const int pbase = blockIdx.y * CP;

    // A fragments (fixed for the whole kernel)
    const int m = qbase + n31;
    bf16x8 axh = *(const bf16x8*)(Apk + (size_t)m * 32 + half * 8);
    bf16x8 axl = *(const bf16x8*)(Apk + (size_t)m * 32 + 16 + half * 8);

    const unsigned short* bp = Ppk + (size_t)(pbase + n31) * 32 + half * 8;
    const float*          np = nhf + pbase + n31;

    f32x16 rbest;
#pragma unroll
    for (int r = 0; r < 16; ++r) rbest[r] = -FLT_MAX;

    bf16x8 bh = *(const bf16x8*)bp;          // ph frag
    bf16x8 bl = *(const bf16x8*)(bp + 16);   // pl frag
    float  nv = *np;                          // -0.5*||p_col||^2
    bp += 32 * 32;  np += 32;

    for (int t = 0; t < TPW; ++t) {
        bf16x8 nbh, nbl; float nnv;
        if (t + 1 < TPW) {                   // prefetch next tile
            nbh = *(const bf16x8*)bp;
            nbl = *(const bf16x8*)(bp + 16);
            nnv = *np;
            bp += 32 * 32;  np += 32;
        }
        f32x16 c;
#pragma unroll
        for (int r = 0; r < 16; ++r) c[r] = nv;   // seed with -0.5*||p||^2 (col-constant)
        c = __builtin_amdgcn_mfma_f32_32x32x16_bf16(axh, bh, c, 0, 0, 0);
        c = __builtin_amdgcn_mfma_f32_32x32x16_bf16(axl, bh, c, 0, 0, 0);
        c = __builtin_amdgcn_mfma_f32_32x32x16_bf16(axh, bl, c, 0, 0, 0);
#pragma unroll
        for (int r = 0; r < 16; ++r) rbest[r] = fmaxf(rbest[r], c[r]);
        bh = nbh; bl = nbl; nv = nnv;
    }

    // max over the 32 point-columns (lanes within each half)
#pragma unroll
    for (int r = 0; r < 16; ++r) {
        float v = rbest[r];
        v = fmaxf(v, __shfl_xor(v, 1, 32));
        v = fmaxf(v, __shfl_xor(v, 2, 32));
        v = fmaxf(v, __shfl_xor(v, 4, 32));
        v = fmaxf(v, __shfl_xor(v, 8, 32));
        v = fmaxf(v, __shfl_xor(v, 16, 32));
        rbest[r] = v;
    }
    if (n31 == 0) {
        float* pp = part + (size_t)blockIdx.y * NQ + qbase + 4 * half;
#pragma unroll
        for (int r = 0; r < 16; ++r) pp[(r & 3) + 8 * (r >> 2)] = rbest[r];
    }
}

// ---------------------------------------------------------------------------
// Final: reduce SCH chunks, dist2 = ||x||^2 - 2*best, bump.
// ---------------------------------------------------------------------------
__global__ __launch_bounds__(256) void knn_final_mfma(const float* __restrict__ x,
                                                      const float* __restrict__ part,
                                                      float* __restrict__ out) {
    const int q = blockIdx.x * 256 + threadIdx.x;
    const float4* xr = (const float4*)(x + (size_t)q * D);
    float4 a = xr[0], b = xr[1], c = xr[2], e = xr[3];
    float x2 = a.x * a.x;
    x2 = fmaf(a.y, a.y, x2); x2 = fmaf(a.z, a.z, x2); x2 = fmaf(a.w, a.w, x2);
    x2 = fmaf(b.x, b.x, x2); x2 = fmaf(b.y, b.y, x2); x2 = fmaf(b.z, b.z, x2); x2 = fmaf(b.w, b.w, x2);
    x2 = fmaf(c.x, c.x, x2); x2 = fmaf(c.y, c.y, x2); x2 = fmaf(c.z, c.z, x2); x2 = fmaf(c.w, c.w, x2);
    x2 = fmaf(e.x, e.x, x2); x2 = fmaf(e.y, e.y, x2); x2 = fmaf(e.z, e.z, x2); x2 = fmaf(e.w, e.w, x2);

    float mbest = -FLT_MAX;
#pragma unroll
    for (int cI = 0; cI < SCH; ++cI) mbest = fmaxf(mbest, part[(size_t)cI * NQ + q]);

    float nn2  = fmaxf(fmaf(-2.f, mbest, x2), 0.f);
    float dist = sqrtf(fmaxf(nn2, 1e-12f));
    float bump = 0.f;
    if (dist < 2.0f) {
        float denom = dist * dist - 4.0f;
        bump = expf(1.0f / denom + 0.25f);
    }
    out[q] = bump;
}

// ===========================================================================
// Fallback path (R2 kernels) if workspace is too small for the MFMA path.
// ===========================================================================
__global__ __launch_bounds__(256) void neg_half_norms(const float* __restrict__ data,
                                                      float* __restrict__ nhn) {
    const int p = blockIdx.x * 256 + threadIdx.x;
    const float4* r = (const float4*)(data + (size_t)p * D);
    float4 a = r[0], b = r[1], c = r[2], e = r[3];
    float n = a.x * a.x;
    n = fmaf(a.y, a.y, n); n = fmaf(a.z, a.z, n); n = fmaf(a.w, a.w, n);
    n = fmaf(b.x, b.x, n); n = fmaf(b.y, b.y, n); n = fmaf(b.z, b.z, n); n = fmaf(b.w, b.w, n);
    n = fmaf(c.x, c.x, n); n = fmaf(c.y, c.y, n); n = fmaf(c.z, c.z, n); n = fmaf(c.w, c.w, n);
    n = fmaf(e.x, e.x, n); n = fmaf(e.y, e.y, n); n = fmaf(e.z, e.z, n); n = fmaf(e.w, e.w, n);
    nhn[p] = -0.5f * n;
}

__global__ __launch_bounds__(256) void knn_partial_fb(const float* __restrict__ x,
                                                      const float* __restrict__ data,
                                                      const float* __restrict__ nhn,
                                                      float* __restrict__ part, int cp) {
    const int q     = blockIdx.x * 256 + threadIdx.x;
    const int pbase = blockIdx.y * cp;
    const float4* xr = (const float4*)(x + (size_t)q * D);
    const float4 xa = xr[0], xb = xr[1], xc = xr[2], xd = xr[3];
    const float* dp = data + (size_t)pbase * D;
    const float* np = nhn + pbase;
    float best = -FLT_MAX;
    for (int i = 0; i < cp; i += 4) {
#pragma unroll
        for (int j = 0; j < 4; ++j) {
            const float* r  = dp + (size_t)(i + j) * D;
            const float  hn = np[i + j];
            float ca = xa.x * r[0];
            ca = fmaf(xa.y, r[1], ca);  ca = fmaf(xa.z, r[2], ca);  ca = fmaf(xa.w, r[3], ca);
            ca = fmaf(xb.x, r[4], ca);  ca = fmaf(xb.y, r[5], ca);  ca = fmaf(xb.z, r[6], ca);
            ca = fmaf(xb.w, r[7], ca);
            float cb = fmaf(xc.x, r[8], hn);
            cb = fmaf(xc.y, r[9],  cb); cb = fmaf(xc.z, r[10], cb); cb = fmaf(xc.w, r[11], cb);
            cb = fmaf(xd.x, r[12], cb); cb = fmaf(xd.y, r[13], cb); cb = fmaf(xd.z, r[14], cb);
            cb = fmaf(xd.w, r[15], cb);
            best = fmaxf(best, ca + cb);
        }
    }
    part[(size_t)blockIdx.y * NQ + q] = best;
}

__global__ __launch_bounds__(256) void knn_final_fb(const float* __restrict__ x,
                                                    const float* __restrict__ part,
                                                    float* __restrict__ out, int S) {
    const int q = blockIdx.x * 256 + threadIdx.x;
    const float4* xr = (const float4*)(x + (size_t)q * D);
    float4 a = xr[0], b = xr[1], c = xr[2], e = xr[3];
    float x2 = a.x * a.x;
    x2 = fmaf(a.y, a.y, x2); x2 = fmaf(a.z, a.z, x2); x2 = fmaf(a.w, a.w, x2);
    x2 = fmaf(b.x, b.x, x2); x2 = fmaf(b.y, b.y, x2); x2 = fmaf(b.z, b.z, x2); x2 = fmaf(b.w, b.w, x2);
    x2 = fmaf(c.x, c.x, x2); x2 = fmaf(c.y, c.y, x2); x2 = fmaf(c.z, c.z, x2); x2 = fmaf(c.w, c.w, x2);
    x2 = fmaf(e.x, e.x, x2); x2 = fmaf(e.y, e.y, x2); x2 = fmaf(e.z, e.z, x2); x2 = fmaf(e.w, e.w, x2);
    float mb = -FLT_MAX;
    for (int cI = 0; cI < S; ++cI) mb = fmaxf(mb, part[(size_t)cI * NQ + q]);
    float nn2  = fmaxf(fmaf(-2.f, mb, x2), 0.f);
    float dist = sqrtf(fmaxf(nn2, 1e-12f));
    float bump = 0.f;
    if (dist < 2.0f) {
        float denom = dist * dist - 4.0f;
        bump = expf(1.0f / denom + 0.25f);
    }
    out[q] = bump;
}

extern "C" void kernel_launch(void* const* d_in, const int* in_sizes, int n_in,
                              void* d_out, int out_size, void* d_ws, size_t ws_size,
                              hipStream_t stream) {
    const float* x    = (const float*)d_in[0];   // [2048,16] fp32
    const float* data = (const float*)d_in[1];   // [65536,16] fp32
    float* out = (float*)d_out;                  // [2048] fp32

    // ws layout (bytes):
    //   Ppk  [0, 4 MiB)              ND*32 bf16
    //   Apk  [4 MiB, +128 KiB)       NQ*32 bf16
    //   nhf  [+256 KiB)              ND fp32
    //   part [+512 KiB)              SCH*NQ fp32
    const size_t off_Apk  = (size_t)ND * 32 * 2;            // 4194304
    const size_t off_nhf  = off_Apk + (size_t)NQ * 32 * 2;  // 4325376
    const size_t off_part = off_nhf + (size_t)ND * 4;       // 4587520
    const size_t needed   = off_part + (size_t)SCH * NQ * 4;// 5111808

    if (ws_size >= needed) {
        unsigned short* Ppk = (unsigned short*)d_ws;
        unsigned short* Apk = (unsigned short*)((char*)d_ws + off_Apk);
        float* nhf  = (float*)((char*)d_ws + off_nhf);
        float* part = (float*)((char*)d_ws + off_part);

        pack_inputs<<<(ND + NQ) / 256, 256, 0, stream>>>(x, data, Ppk, Apk, nhf);
        knn_mfma<<<dim3(NQ / 128, SCH), 256, 0, stream>>>(Apk, Ppk, nhf, part);
        knn_final_mfma<<<NQ / 256, 256, 0, stream>>>(x, part, out);
    } else {
        // Fallback: fp32 scalar-pipe path (R2), S capped small to keep the
        // final reduce cheap.
        int S = 32;
        while (S > 1 && (size_t)(ND + S * NQ) * sizeof(float) > ws_size) S >>= 1;
        const int cp = ND / S;
        float* nhn  = (float*)d_ws;
        float* part = (float*)d_ws + ND;
        neg_half_norms<<<ND / 256, 256, 0, stream>>>(data, nhn);
        knn_partial_fb<<<dim3(NQ / 256, S), 256, 0, stream>>>(x, data, nhn, part, cp);
        knn_final_fb<<<NQ / 256, 256, 0, stream>>>(x, part, out, S);
    }
}

// Round 4
// 85.050 us; speedup vs baseline: 5.3940x; 1.0623x over previous
//
#include <hip/hip_runtime.h>
#include <float.h>
#include <math.h>

// Problem constants (fixed by reference setup_inputs)
constexpr int NQ = 2048;    // queries
constexpr int ND = 65536;   // data points
constexpr int D  = 16;      // dims

// ---- MFMA-path tiling ----
constexpr int SCH   = 64;           // point chunks (grid.y)
constexpr int CP    = ND / SCH;     // 1024 points per chunk
constexpr int TPW   = CP / 32;      // 32 point-tiles (32 pts) per wave
constexpr int NPAIR = TPW / 2;      // 16 tile-pairs

typedef short bf16x8 __attribute__((ext_vector_type(8)));
typedef float f32x16 __attribute__((ext_vector_type(16)));

__device__ __forceinline__ unsigned short f2bf(float f) {  // RNE fp32->bf16
    unsigned u = __float_as_uint(f);
    u += 0x7FFFu + ((u >> 16) & 1u);
    return (unsigned short)(u >> 16);
}
__device__ __forceinline__ float bf2f(unsigned short h) {
    return __uint_as_float(((unsigned)h) << 16);
}

// ---------------------------------------------------------------------------
// Pack kernel (data only): Ppk[ND][32] = [ph(16)|pl(16)] bf16,
//                          nhf[ND]    = -0.5*||p||^2 (fp32, exact-ish)
// ---------------------------------------------------------------------------
__global__ __launch_bounds__(256) void pack_data(const float* __restrict__ data,
                                                 unsigned short* __restrict__ Ppk,
                                                 float* __restrict__ nhf) {
    const int p = blockIdx.x * 256 + threadIdx.x;
    const float4* r4 = (const float4*)(data + (size_t)p * D);
    float4 a = r4[0], b = r4[1], c = r4[2], e = r4[3];
    float v[16] = {a.x, a.y, a.z, a.w, b.x, b.y, b.z, b.w,
                   c.x, c.y, c.z, c.w, e.x, e.y, e.z, e.w};
    unsigned short row[32];
    float n = 0.f;
#pragma unroll
    for (int k = 0; k < 16; ++k) {
        n = fmaf(v[k], v[k], n);
        unsigned short h = f2bf(v[k]);
        row[k]      = h;
        row[16 + k] = f2bf(v[k] - bf2f(h));   // exact residual, rounded to bf16
    }
    uint4* w4 = (uint4*)(Ppk + (size_t)p * 32);
    const uint4* rr = (const uint4*)row;
    w4[0] = rr[0]; w4[1] = rr[1]; w4[2] = rr[2]; w4[3] = rr[3];
    nhf[p] = -0.5f * n;
}

// ---------------------------------------------------------------------------
// Main kernel: per wave, 32 queries x one 1024-point chunk.
//   best[q] = max_p ( x_q . p - 0.5*||p||^2 )   (argmin dist2 == argmax this)
// 3x mfma_f32_32x32x16_bf16 per 32-pt tile (hi*hi + lo*hi + hi*lo), C seeded
// with -0.5*||p||^2. Tile PAIRS with ping-pong prefetch; per-pair epilogue is
// 16x v_max3_f32 (rbest, c0, c1).
// A-frag built in-kernel from fp32 x: lane holds x[qbase+(l&31)][ (l>>5)*8 + j ].
// C/D: col = lane&31, row = (reg&3) + 8*(reg>>2) + 4*(lane>>5)  [m74/m101].
// ---------------------------------------------------------------------------
__global__ __launch_bounds__(256, 4) void knn_mfma(const float* __restrict__ x,
                                                   const unsigned short* __restrict__ Ppk,
                                                   const float* __restrict__ nhf,
                                                   float* __restrict__ part) {
    const int tid  = threadIdx.x;
    const int w    = tid >> 6;
    const int l    = tid & 63;
    const int half = l >> 5;
    const int n31  = l & 31;
    const int qbase = blockIdx.x * 128 + w * 32;   // 4 waves x 32 queries
    const int pbase = blockIdx.y * CP;

    // Build A fragments (hi/lo bf16) from raw fp32 x — once per wave.
    const float* xr = x + (size_t)(qbase + n31) * D + half * 8;
    float4 x0 = *(const float4*)xr;
    float4 x1 = *(const float4*)(xr + 4);
    const float xv[8] = {x0.x, x0.y, x0.z, x0.w, x1.x, x1.y, x1.z, x1.w};
    bf16x8 axh, axl;
#pragma unroll
    for (int k = 0; k < 8; ++k) {
        unsigned short h = f2bf(xv[k]);
        axh[k] = (short)h;
        axl[k] = (short)f2bf(xv[k] - bf2f(h));
    }

    // B-side pointers (per-lane point column)
    const unsigned short* bp = Ppk + (size_t)(pbase + n31) * 32 + half * 8;
    const float*          np = nhf + pbase + n31;
    // tile t: bh at bp + t*1024, bl at +16; nv at np + t*32

#define LDH(t) (*(const bf16x8*)(bp + (size_t)(t) * 1024))
#define LDL(t) (*(const bf16x8*)(bp + (size_t)(t) * 1024 + 16))
#define LDN(t) (np[(size_t)(t) * 32])

    f32x16 rbest;
#pragma unroll
    for (int r = 0; r < 16; ++r) rbest[r] = -FLT_MAX;

    auto compute_pair = [&](bf16x8 h0, bf16x8 l0, float n0,
                            bf16x8 h1, bf16x8 l1, float n1) {
        f32x16 c0, c1;
#pragma unroll
        for (int r = 0; r < 16; ++r) { c0[r] = n0; c1[r] = n1; }
        c0 = __builtin_amdgcn_mfma_f32_32x32x16_bf16(axh, h0, c0, 0, 0, 0);
        c1 = __builtin_amdgcn_mfma_f32_32x32x16_bf16(axh, h1, c1, 0, 0, 0);
        c0 = __builtin_amdgcn_mfma_f32_32x32x16_bf16(axl, h0, c0, 0, 0, 0);
        c1 = __builtin_amdgcn_mfma_f32_32x32x16_bf16(axl, h1, c1, 0, 0, 0);
        c0 = __builtin_amdgcn_mfma_f32_32x32x16_bf16(axh, l0, c0, 0, 0, 0);
        c1 = __builtin_amdgcn_mfma_f32_32x32x16_bf16(axh, l1, c1, 0, 0, 0);
#pragma unroll
        for (int r = 0; r < 16; ++r)
            rbest[r] = fmaxf(rbest[r], fmaxf(c0[r], c1[r]));  // -> v_max3_f32
    };

    // Ping-pong over tile pairs: pair p = tiles {2p, 2p+1}
    bf16x8 Ah0 = LDH(0), Al0 = LDL(0), Ah1 = LDH(1), Al1 = LDL(1);
    float  An0 = LDN(0), An1 = LDN(1);
    bf16x8 Bh0, Bl0, Bh1, Bl1;
    float  Bn0, Bn1;

    for (int p = 0; p < NPAIR; p += 2) {
        const int tB = (p + 1) * 2;
        Bh0 = LDH(tB);     Bl0 = LDL(tB);     Bn0 = LDN(tB);
        Bh1 = LDH(tB + 1); Bl1 = LDL(tB + 1); Bn1 = LDN(tB + 1);
        compute_pair(Ah0, Al0, An0, Ah1, Al1, An1);
        if (p + 2 < NPAIR) {
            const int tA = (p + 2) * 2;
            Ah0 = LDH(tA);     Al0 = LDL(tA);     An0 = LDN(tA);
            Ah1 = LDH(tA + 1); Al1 = LDL(tA + 1); An1 = LDN(tA + 1);
        }
        compute_pair(Bh0, Bl0, Bn0, Bh1, Bl1, Bn1);
    }
#undef LDH
#undef LDL
#undef LDN

    // max over the 32 point-columns (lanes within each half)
#pragma unroll
    for (int r = 0; r < 16; ++r) {
        float v = rbest[r];
        v = fmaxf(v, __shfl_xor(v, 1, 32));
        v = fmaxf(v, __shfl_xor(v, 2, 32));
        v = fmaxf(v, __shfl_xor(v, 4, 32));
        v = fmaxf(v, __shfl_xor(v, 8, 32));
        v = fmaxf(v, __shfl_xor(v, 16, 32));
        rbest[r] = v;
    }
    if (n31 == 0) {
        float* pp = part + (size_t)blockIdx.y * NQ + qbase + 4 * half;
#pragma unroll
        for (int r = 0; r < 16; ++r) pp[(r & 3) + 8 * (r >> 2)] = rbest[r];
    }
}

// ---------------------------------------------------------------------------
// Final: reduce SCH chunks, dist2 = ||x||^2 - 2*best, bump.
// Reads are lane-contiguous per chunk iteration (coalesced).
// ---------------------------------------------------------------------------
__global__ __launch_bounds__(256) void knn_final(const float* __restrict__ x,
                                                 const float* __restrict__ part,
                                                 float* __restrict__ out) {
    const int q = blockIdx.x * 256 + threadIdx.x;
    const float4* xr = (const float4*)(x + (size_t)q * D);
    float4 a = xr[0], b = xr[1], c = xr[2], e = xr[3];
    float x2 = a.x * a.x;
    x2 = fmaf(a.y, a.y, x2); x2 = fmaf(a.z, a.z, x2); x2 = fmaf(a.w, a.w, x2);
    x2 = fmaf(b.x, b.x, x2); x2 = fmaf(b.y, b.y, x2); x2 = fmaf(b.z, b.z, x2); x2 = fmaf(b.w, b.w, x2);
    x2 = fmaf(c.x, c.x, x2); x2 = fmaf(c.y, c.y, x2); x2 = fmaf(c.z, c.z, x2); x2 = fmaf(c.w, c.w, x2);
    x2 = fmaf(e.x, e.x, x2); x2 = fmaf(e.y, e.y, x2); x2 = fmaf(e.z, e.z, x2); x2 = fmaf(e.w, e.w, x2);

    float mbest = -FLT_MAX;
#pragma unroll
    for (int cI = 0; cI < SCH; ++cI) mbest = fmaxf(mbest, part[(size_t)cI * NQ + q]);

    float nn2  = fmaxf(fmaf(-2.f, mbest, x2), 0.f);
    float dist = sqrtf(fmaxf(nn2, 1e-12f));
    float bump = 0.f;
    if (dist < 2.0f) {                      // RADIUS = 2
        float denom = dist * dist - 4.0f;   // d^2 - r^2
        bump = expf(1.0f / denom + 0.25f);  // DECAY/denom + DECAY/r^2
    }
    out[q] = bump;
}

// ===========================================================================
// Fallback (fp32 scalar-pipe path) if workspace is too small for MFMA path.
// ===========================================================================
__global__ __launch_bounds__(256) void neg_half_norms(const float* __restrict__ data,
                                                      float* __restrict__ nhn) {
    const int p = blockIdx.x * 256 + threadIdx.x;
    const float4* r = (const float4*)(data + (size_t)p * D);
    float4 a = r[0], b = r[1], c = r[2], e = r[3];
    float n = a.x * a.x;
    n = fmaf(a.y, a.y, n); n = fmaf(a.z, a.z, n); n = fmaf(a.w, a.w, n);
    n = fmaf(b.x, b.x, n); n = fmaf(b.y, b.y, n); n = fmaf(b.z, b.z, n); n = fmaf(b.w, b.w, n);
    n = fmaf(c.x, c.x, n); n = fmaf(c.y, c.y, n); n = fmaf(c.z, c.z, n); n = fmaf(c.w, c.w, n);
    n = fmaf(e.x, e.x, n); n = fmaf(e.y, e.y, n); n = fmaf(e.z, e.z, n); n = fmaf(e.w, e.w, n);
    nhn[p] = -0.5f * n;
}

__global__ __launch_bounds__(256) void knn_partial_fb(const float* __restrict__ x,
                                                      const float* __restrict__ data,
                                                      const float* __restrict__ nhn,
                                                      float* __restrict__ part, int cp) {
    const int q     = blockIdx.x * 256 + threadIdx.x;
    const int pbase = blockIdx.y * cp;
    const float4* xr = (const float4*)(x + (size_t)q * D);
    const float4 xa = xr[0], xb = xr[1], xc = xr[2], xd = xr[3];
    const float* dp = data + (size_t)pbase * D;
    const float* np = nhn + pbase;
    float best = -FLT_MAX;
    for (int i = 0; i < cp; i += 4) {
#pragma unroll
        for (int j = 0; j < 4; ++j) {
            const float* r  = dp + (size_t)(i + j) * D;
            const float  hn = np[i + j];
            float ca = xa.x * r[0];
            ca = fmaf(xa.y, r[1], ca);  ca = fmaf(xa.z, r[2], ca);  ca = fmaf(xa.w, r[3], ca);
            ca = fmaf(xb.x, r[4], ca);  ca = fmaf(xb.y, r[5], ca);  ca = fmaf(xb.z, r[6], ca);
            ca = fmaf(xb.w, r[7], ca);
            float cb = fmaf(xc.x, r[8], hn);
            cb = fmaf(xc.y, r[9],  cb); cb = fmaf(xc.z, r[10], cb); cb = fmaf(xc.w, r[11], cb);
            cb = fmaf(xd.x, r[12], cb); cb = fmaf(xd.y, r[13], cb); cb = fmaf(xd.z, r[14], cb);
            cb = fmaf(xd.w, r[15], cb);
            best = fmaxf(best, ca + cb);
        }
    }
    part[(size_t)blockIdx.y * NQ + q] = best;
}

__global__ __launch_bounds__(256) void knn_final_fb(const float* __restrict__ x,
                                                    const float* __restrict__ part,
                                                    float* __restrict__ out, int S) {
    const int q = blockIdx.x * 256 + threadIdx.x;
    const float4* xr = (const float4*)(x + (size_t)q * D);
    float4 a = xr[0], b = xr[1], c = xr[2], e = xr[3];
    float x2 = a.x * a.x;
    x2 = fmaf(a.y, a.y, x2); x2 = fmaf(a.z, a.z, x2); x2 = fmaf(a.w, a.w, x2);
    x2 = fmaf(b.x, b.x, x2); x2 = fmaf(b.y, b.y, x2); x2 = fmaf(b.z, b.z, x2); x2 = fmaf(b.w, b.w, x2);
    x2 = fmaf(c.x, c.x, x2); x2 = fmaf(c.y, c.y, x2); x2 = fmaf(c.z, c.z, x2); x2 = fmaf(c.w, c.w, x2);
    x2 = fmaf(e.x, e.x, x2); x2 = fmaf(e.y, e.y, x2); x2 = fmaf(e.z, e.z, x2); x2 = fmaf(e.w, e.w, x2);
    float mb = -FLT_MAX;
    for (int cI = 0; cI < S; ++cI) mb = fmaxf(mb, part[(size_t)cI * NQ + q]);
    float nn2  = fmaxf(fmaf(-2.f, mb, x2), 0.f);
    float dist = sqrtf(fmaxf(nn2, 1e-12f));
    float bump = 0.f;
    if (dist < 2.0f) {
        float denom = dist * dist - 4.0f;
        bump = expf(1.0f / denom + 0.25f);
    }
    out[q] = bump;
}

extern "C" void kernel_launch(void* const* d_in, const int* in_sizes, int n_in,
                              void* d_out, int out_size, void* d_ws, size_t ws_size,
                              hipStream_t stream) {
    const float* x    = (const float*)d_in[0];   // [2048,16] fp32
    const float* data = (const float*)d_in[1];   // [65536,16] fp32
    float* out = (float*)d_out;                  // [2048] fp32

    // ws layout (bytes):
    //   Ppk  [0, 4 MiB)          ND*32 bf16
    //   nhf  [4 MiB, +256 KiB)   ND fp32
    //   part [+256 KiB)          SCH*NQ fp32
    const size_t off_nhf  = (size_t)ND * 32 * 2;             // 4194304
    const size_t off_part = off_nhf + (size_t)ND * 4;        // 4456448
    const size_t needed   = off_part + (size_t)SCH * NQ * 4; // 4980736

    if (ws_size >= needed) {
        unsigned short* Ppk = (unsigned short*)d_ws;
        float* nhf  = (float*)((char*)d_ws + off_nhf);
        float* part = (float*)((char*)d_ws + off_part);

        pack_data<<<ND / 256, 256, 0, stream>>>(data, Ppk, nhf);
        knn_mfma<<<dim3(NQ / 128, SCH), 256, 0, stream>>>(x, Ppk, nhf, part);
        knn_final<<<NQ / 256, 256, 0, stream>>>(x, part, out);
    } else {
        int S = 32;
        while (S > 1 && (size_t)(ND + S * NQ) * sizeof(float) > ws_size) S >>= 1;
        const int cp = ND / S;
        float* nhn  = (float*)d_ws;
        float* part = (float*)d_ws + ND;
        neg_half_norms<<<ND / 256, 256, 0, stream>>>(data, nhn);
        knn_partial_fb<<<dim3(NQ / 256, S), 256, 0, stream>>>(x, data, nhn, part, cp);
        knn_final_fb<<<NQ / 256, 256, 0, stream>>>(x, part, out, S);
    }
}